// Round 12
// baseline (259.710 us; speedup 1.0000x reference)
//
#include <hip/hip_runtime.h>
#include <math.h>

#define NNODES 50000
#define NEDGES 1600000
#define NB 391              // ceil(50000/128) buckets of 128 nodes
#define NBP 400             // padded

__device__ __forceinline__ float lrelu(float v) { return v > 0.f ? v : 0.2f * v; }

template<int SEL>
__device__ __forceinline__ float fp8d(unsigned u) {  // decode byte SEL of u (e4m3 OCP)
    return __builtin_amdgcn_cvt_f32_fp8((int)u, SEL);
}

// ---- pad x (N x 11) -> xp (N x 12, last col 0) ----
__global__ void padx_kernel(const float* __restrict__ x, float* __restrict__ xp, int N) {
    int t = blockIdx.x * blockDim.x + threadIdx.x;
    if (t >= N * 12) return;
    int n = t / 12, k = t - n * 12;
    xp[t] = (k < 11) ? x[n * 11 + k] : 0.f;
}

// ---- va[k][h] = sum_f W[k][h*F+f] * a[h][f], padded to 8 heads ----
template<int DIN, int H, int F>
__global__ void va_kernel(const float* __restrict__ W, const float* __restrict__ a_s,
                          const float* __restrict__ a_d, float* __restrict__ va_s,
                          float* __restrict__ va_d, int DINEFF) {
    int t = threadIdx.x;
    if (t >= DIN * 8) return;
    int k = t / 8, h = t - k * 8;
    float s = 0.f, d = 0.f;
    if (h < H && k < DINEFF) {
        for (int f = 0; f < F; ++f) {
            float w = W[k * (H * F) + h * F + f];
            s = fmaf(w, a_s[h * F + f], s);
            d = fmaf(w, a_d[h * F + f], d);
        }
    }
    va_s[t] = s;
    va_d[t] = d;
}

// ---- asp[n*8+h] = sum_k X[n][k]*va_s[k][h]; adp likewise ----
template<int DIN>
__global__ void alphap_kernel(const float* __restrict__ X, const float* __restrict__ va_s,
                              const float* __restrict__ va_d, float* __restrict__ asp,
                              float* __restrict__ adp, int N) {
    __shared__ float vs[DIN * 8], vd[DIN * 8];
    for (int i = threadIdx.x; i < DIN * 8; i += blockDim.x) { vs[i] = va_s[i]; vd[i] = va_d[i]; }
    __syncthreads();
    int t = blockIdx.x * blockDim.x + threadIdx.x;
    if (t >= N * 8) return;
    int n = t / 8, h = t - n * 8;
    const float* xr = X + (size_t)n * DIN;
    float s = 0.f, d = 0.f;
    for (int k = 0; k < DIN; ++k) {
        float xv = xr[k];
        s = fmaf(xv, vs[k * 8 + h], s);
        d = fmaf(xv, vd[k * 8 + h], d);
    }
    asp[t] = s;
    adp[t] = d;
}

// ==== CSR build: 2-level counting sort by dst ====
__global__ void bucket_hist_kernel(const int* __restrict__ dst, int* __restrict__ bcnt, int E) {
    __shared__ int h[NBP];
    for (int i = threadIdx.x; i < NBP; i += blockDim.x) h[i] = 0;
    __syncthreads();
    for (int e = blockIdx.x * blockDim.x + threadIdx.x; e < E; e += gridDim.x * blockDim.x)
        atomicAdd(&h[dst[e] >> 7], 1);
    __syncthreads();
    for (int i = threadIdx.x; i < NB; i += blockDim.x)
        if (h[i]) atomicAdd(&bcnt[i], h[i]);
}

__global__ void bucket_scan_kernel(const int* __restrict__ bcnt, int* __restrict__ bbase,
                                   int* __restrict__ bcur, int* __restrict__ off, int E) {
    __shared__ int ls[512];
    int t = threadIdx.x;
    int c = (t < NB) ? bcnt[t] : 0;
    ls[t] = c;
    __syncthreads();
    for (int o = 1; o < 512; o <<= 1) {
        int u = (t >= o) ? ls[t - o] : 0;
        __syncthreads();
        ls[t] += u;
        __syncthreads();
    }
    if (t < NB) {
        int ex = ls[t] - c;
        bbase[t] = ex;
        bcur[t] = ex;
    }
    if (t == 0) { bbase[NB] = E; off[NNODES] = E; }
}

#define BA_CHUNK 8192
#define BA_THREADS 1024
__global__ void binA_kernel(const int* __restrict__ src, const int* __restrict__ dst,
                            int* __restrict__ bcur, unsigned* __restrict__ tmp, int E) {
    __shared__ unsigned sv[BA_CHUNK];
    __shared__ unsigned short sb[BA_CHUNK];
    __shared__ int cnt[NBP], basel[NBP];
    int tid = threadIdx.x;
    for (int i = tid; i < NBP; i += BA_THREADS) cnt[i] = 0;
    __syncthreads();
    int e0 = blockIdx.x * BA_CHUNK;
    int lim = min(BA_CHUNK, E - e0);
#pragma unroll
    for (int k = 0; k < BA_CHUNK / BA_THREADS; ++k) {
        int i = k * BA_THREADS + tid;
        if (i < lim) {
            int s = src[e0 + i], d = dst[e0 + i];
            sv[i] = (unsigned)s | ((unsigned)(d & 127) << 17);
            int b = d >> 7;
            sb[i] = (unsigned short)b;
            atomicAdd(&cnt[b], 1);
        }
    }
    __syncthreads();
    for (int i = tid; i < NB; i += BA_THREADS)
        basel[i] = cnt[i] ? atomicAdd(&bcur[i], cnt[i]) : 0;
    __syncthreads();
#pragma unroll
    for (int k = 0; k < BA_CHUNK / BA_THREADS; ++k) {
        int i = k * BA_THREADS + tid;
        if (i < lim) {
            int pos = atomicAdd(&basel[sb[i]], 1);
            tmp[pos] = sv[i];
        }
    }
}

__global__ void binB_kernel(const int* __restrict__ bbase, const unsigned* __restrict__ tmp,
                            int* __restrict__ off, int* __restrict__ esrc, int N) {
    __shared__ int ncnt[128], ncur[128], ls[128];
    int b = blockIdx.x;
    int tid = threadIdx.x;   // 256 threads
    int lo = bbase[b], hi = bbase[b + 1];
    if (tid < 128) ncnt[tid] = 0;
    __syncthreads();
    for (int i = lo + tid; i < hi; i += 256)
        atomicAdd(&ncnt[tmp[i] >> 17], 1);
    __syncthreads();
    if (tid < 128) ls[tid] = ncnt[tid];
    __syncthreads();
    for (int o = 1; o < 128; o <<= 1) {
        int u = (tid >= o && tid < 128) ? ls[tid - o] : 0;
        __syncthreads();
        if (tid < 128) ls[tid] += u;
        __syncthreads();
    }
    if (tid < 128) {
        int ex = lo + ls[tid] - ncnt[tid];
        int n = b * 128 + tid;
        if (n < N) off[n] = ex;
        ncur[tid] = ex;
    }
    __syncthreads();
    for (int i = lo + tid; i < hi; i += 256) {
        unsigned v = tmp[i];
        int pos = atomicAdd(&ncur[v >> 17], 1);
        esrc[pos] = (int)(v & 0x1FFFFu);
    }
}

// ---- layer-1 gather on raw x rows: 3 thr/node, LDS-staged esrc, unroll-4 ----
#define G1_NODES 128
#define G1_THREADS (G1_NODES * 3)
#define G1_ECAP 4800
__global__ void gather1_kernel(const int* __restrict__ off, const int* __restrict__ esrc,
                               const float* __restrict__ asp, const float* __restrict__ adp,
                               const float* __restrict__ xp, float* __restrict__ aggX, int N) {
    __shared__ int se[G1_ECAP];
    int li = threadIdx.x;
    int n0 = blockIdx.x * G1_NODES;
    int nend = min(n0 + G1_NODES, N);
    int base = off[n0];
    int cnt = off[nend] - base;
    bool staged = (cnt <= G1_ECAP);
    if (staged) for (int i = li; i < cnt; i += G1_THREADS) se[i] = esrc[base + i];
    __syncthreads();
    int node = n0 + li / 3;
    int j = li % 3;
    if (node >= N) return;
    const float4 advA = *(const float4*)(adp + (size_t)node * 8);
    const float2 advB = *(const float2*)(adp + (size_t)node * 8 + 4);
    const float4* xp4 = (const float4*)xp;
    int p0 = off[node], p1 = off[node + 1];
    float4 ac[6];
    float d[6];
#pragma unroll
    for (int u = 0; u < 6; ++u) { ac[u] = make_float4(0.f, 0.f, 0.f, 0.f); d[u] = 0.f; }
#define G1_EDGE(asA, asB, xv)                                                        \
    {                                                                                \
        float a0 = __expf(lrelu(asA.x + advA.x));                                    \
        float a1 = __expf(lrelu(asA.y + advA.y));                                    \
        float a2 = __expf(lrelu(asA.z + advA.z));                                    \
        float a3 = __expf(lrelu(asA.w + advA.w));                                    \
        float a4 = __expf(lrelu(asB.x + advB.x));                                    \
        float a5 = __expf(lrelu(asB.y + advB.y));                                    \
        d[0] += a0; d[1] += a1; d[2] += a2; d[3] += a3; d[4] += a4; d[5] += a5;      \
        ac[0].x = fmaf(a0, xv.x, ac[0].x); ac[0].y = fmaf(a0, xv.y, ac[0].y);        \
        ac[0].z = fmaf(a0, xv.z, ac[0].z); ac[0].w = fmaf(a0, xv.w, ac[0].w);        \
        ac[1].x = fmaf(a1, xv.x, ac[1].x); ac[1].y = fmaf(a1, xv.y, ac[1].y);        \
        ac[1].z = fmaf(a1, xv.z, ac[1].z); ac[1].w = fmaf(a1, xv.w, ac[1].w);        \
        ac[2].x = fmaf(a2, xv.x, ac[2].x); ac[2].y = fmaf(a2, xv.y, ac[2].y);        \
        ac[2].z = fmaf(a2, xv.z, ac[2].z); ac[2].w = fmaf(a2, xv.w, ac[2].w);        \
        ac[3].x = fmaf(a3, xv.x, ac[3].x); ac[3].y = fmaf(a3, xv.y, ac[3].y);        \
        ac[3].z = fmaf(a3, xv.z, ac[3].z); ac[3].w = fmaf(a3, xv.w, ac[3].w);        \
        ac[4].x = fmaf(a4, xv.x, ac[4].x); ac[4].y = fmaf(a4, xv.y, ac[4].y);        \
        ac[4].z = fmaf(a4, xv.z, ac[4].z); ac[4].w = fmaf(a4, xv.w, ac[4].w);        \
        ac[5].x = fmaf(a5, xv.x, ac[5].x); ac[5].y = fmaf(a5, xv.y, ac[5].y);        \
        ac[5].z = fmaf(a5, xv.z, ac[5].z); ac[5].w = fmaf(a5, xv.w, ac[5].w);        \
    }
#define G1_LOOP(FS)                                                                  \
    {                                                                                \
        for (; q + 4 <= qe; q += 4) {                                                \
            int s0 = FS(q), s1 = FS(q + 1), s2 = FS(q + 2), s3 = FS(q + 3);          \
            float4 A0 = *(const float4*)(asp + (size_t)s0 * 8);                      \
            float2 B0 = *(const float2*)(asp + (size_t)s0 * 8 + 4);                  \
            float4 X0 = xp4[(size_t)s0 * 3 + j];                                     \
            float4 A1 = *(const float4*)(asp + (size_t)s1 * 8);                      \
            float2 B1 = *(const float2*)(asp + (size_t)s1 * 8 + 4);                  \
            float4 X1 = xp4[(size_t)s1 * 3 + j];                                     \
            float4 A2 = *(const float4*)(asp + (size_t)s2 * 8);                      \
            float2 B2 = *(const float2*)(asp + (size_t)s2 * 8 + 4);                  \
            float4 X2 = xp4[(size_t)s2 * 3 + j];                                     \
            float4 A3 = *(const float4*)(asp + (size_t)s3 * 8);                      \
            float2 B3 = *(const float2*)(asp + (size_t)s3 * 8 + 4);                  \
            float4 X3 = xp4[(size_t)s3 * 3 + j];                                     \
            G1_EDGE(A0, B0, X0) G1_EDGE(A1, B1, X1)                                  \
            G1_EDGE(A2, B2, X2) G1_EDGE(A3, B3, X3)                                  \
        }                                                                            \
        for (; q < qe; ++q) {                                                        \
            int s0 = FS(q);                                                          \
            float4 A0 = *(const float4*)(asp + (size_t)s0 * 8);                      \
            float2 B0 = *(const float2*)(asp + (size_t)s0 * 8 + 4);                  \
            float4 X0 = xp4[(size_t)s0 * 3 + j];                                     \
            G1_EDGE(A0, B0, X0)                                                      \
        }                                                                            \
    }
#define G1_SE(i) se[i]
#define G1_GE(i) esrc[i]
    if (staged) {
        int q = p0 - base, qe = p1 - base;
        G1_LOOP(G1_SE)
    } else {
        int q = p0, qe = p1;
        G1_LOOP(G1_GE)
    }
#undef G1_EDGE
#undef G1_LOOP
    float4* o4 = (float4*)aggX;
#pragma unroll
    for (int u = 0; u < 6; ++u) {
        float r = 1.f / (d[u] + 1e-12f);
        float4 a = ac[u];
        a.x *= r; a.y *= r; a.z *= r; a.w *= r;
        o4[((size_t)node * 6 + u) * 3 + j] = a;
    }
}

// ---- out1[n][96] = elu( aggX[n][h] @ W1[:, head block] ) ----
__global__ void gemmL1_kernel(const float* __restrict__ aggX, const float* __restrict__ W1,
                              float* __restrict__ out1, int N) {
    __shared__ float Wl[12 * 96];
    for (int i = threadIdx.x; i < 12 * 96; i += blockDim.x) Wl[i] = (i < 11 * 96) ? W1[i] : 0.f;
    __syncthreads();
    int t = blockIdx.x * blockDim.x + threadIdx.x;
    if (t >= N * 24) return;
    int n = t / 24, q = t - n * 24;
    int h = q / 4, c = q * 4;
    const float* ag = aggX + ((size_t)n * 6 + h) * 12;
    float4 acc = {0, 0, 0, 0};
#pragma unroll
    for (int k = 0; k < 12; ++k) {
        float xv = ag[k];
        acc.x = fmaf(xv, Wl[k * 96 + c + 0], acc.x);
        acc.y = fmaf(xv, Wl[k * 96 + c + 1], acc.y);
        acc.z = fmaf(xv, Wl[k * 96 + c + 2], acc.z);
        acc.w = fmaf(xv, Wl[k * 96 + c + 3], acc.w);
    }
    acc.x = acc.x > 0.f ? acc.x : expm1f(acc.x);
    acc.y = acc.y > 0.f ? acc.y : expm1f(acc.y);
    acc.z = acc.z > 0.f ? acc.z : expm1f(acc.z);
    acc.w = acc.w > 0.f ? acc.w : expm1f(acc.w);
    ((float4*)out1)[(size_t)n * 24 + q] = acc;
}

// ---- h2 = out1 @ W2, stored fp8 e4m3 (HW RNE cvt); float4 X loads; 1024-thr blocks ----
template<int DIN, int C, int NPT>
__global__ void gemm_fp8_kernel(const float* __restrict__ X, const float* __restrict__ W,
                                unsigned* __restrict__ Out, int N) {
    constexpr int Q = C / 4;
    __shared__ float4 Wl[DIN * Q];
    for (int i = threadIdx.x; i < DIN * Q; i += blockDim.x) Wl[i] = ((const float4*)W)[i];
    __syncthreads();
    int t = blockIdx.x * blockDim.x + threadIdx.x;
    int g = t / Q, q = t - g * Q;
    int n0 = g * NPT;
    if (n0 >= N) return;
    const float4* X4 = (const float4*)X;
    float4 acc[NPT];
#pragma unroll
    for (int u = 0; u < NPT; ++u) acc[u] = make_float4(0.f, 0.f, 0.f, 0.f);
#pragma unroll 2
    for (int k4 = 0; k4 < DIN / 4; ++k4) {
        float4 xv[NPT];
#pragma unroll
        for (int u = 0; u < NPT; ++u) xv[u] = X4[(size_t)(n0 + u) * (DIN / 4) + k4];
#pragma unroll
        for (int i = 0; i < 4; ++i) {
            float4 w = Wl[(k4 * 4 + i) * Q + q];
#pragma unroll
            for (int u = 0; u < NPT; ++u) {
                float xs = (i == 0) ? xv[u].x : (i == 1) ? xv[u].y : (i == 2) ? xv[u].z : xv[u].w;
                acc[u].x = fmaf(xs, w.x, acc[u].x);
                acc[u].y = fmaf(xs, w.y, acc[u].y);
                acc[u].z = fmaf(xs, w.z, acc[u].z);
                acc[u].w = fmaf(xs, w.w, acc[u].w);
            }
        }
    }
#pragma unroll
    for (int u = 0; u < NPT; ++u) {
        int pk = __builtin_amdgcn_cvt_pk_fp8_f32(acc[u].x, acc[u].y, 0, false);
        pk     = __builtin_amdgcn_cvt_pk_fp8_f32(acc[u].z, acc[u].w, pk, true);
        Out[(size_t)(n0 + u) * Q + q] = (unsigned)pk;
    }
}

// ---- layer-2 gather: 18 thr/node (one uint2 = 8 fp8 ch each), LDS-staged esrc,
//      unroll-8 (deep MLP), fused elu + block pool.  block = 576 thr = 32 nodes x 18 ----
#define G2_NODES 32
#define G2_TPN 18
#define G2_THREADS (G2_NODES * G2_TPN)
#define G2_ECAP 1600
__global__ void gather2_kernel(const int* __restrict__ off, const int* __restrict__ esrc,
                               const float* __restrict__ asp, const float* __restrict__ adp,
                               const uint2* __restrict__ h2t2, float* __restrict__ pooled, int N) {
    __shared__ float sp[144];
    __shared__ int se[G2_ECAP];
    int li = threadIdx.x;
    int n0 = blockIdx.x * G2_NODES;
    int nend = min(n0 + G2_NODES, N);
    int base = off[n0];
    int cnt = off[nend] - base;
    bool staged = (cnt <= G2_ECAP);
    if (staged) for (int i = li; i < cnt; i += G2_THREADS) se[i] = esrc[base + i];
    if (li < 144) sp[li] = 0.f;
    __syncthreads();
    int node = n0 + li / G2_TPN;
    int j = li % G2_TPN;        // channels [8j, 8j+8)
    if (node < N) {
        int h = j / 3;          // 24 ch per head = 3 uint2 per head
        float adv = adp[(size_t)node * 8 + h];
        int p0 = off[node], p1 = off[node + 1];
        float acc[8];
#pragma unroll
        for (int c = 0; c < 8; ++c) acc[c] = 0.f;
        float den = 0.f;
#define G2_EDGE(ev, v)                                                     \
    {                                                                      \
        float att = __expf(lrelu(ev + adv));                               \
        den += att;                                                        \
        acc[0] = fmaf(att, fp8d<0>(v.x), acc[0]);                          \
        acc[1] = fmaf(att, fp8d<1>(v.x), acc[1]);                          \
        acc[2] = fmaf(att, fp8d<2>(v.x), acc[2]);                          \
        acc[3] = fmaf(att, fp8d<3>(v.x), acc[3]);                          \
        acc[4] = fmaf(att, fp8d<0>(v.y), acc[4]);                          \
        acc[5] = fmaf(att, fp8d<1>(v.y), acc[5]);                          \
        acc[6] = fmaf(att, fp8d<2>(v.y), acc[6]);                          \
        acc[7] = fmaf(att, fp8d<3>(v.y), acc[7]);                          \
    }
#define G2_LOOP(FS)                                                                        \
    {                                                                                      \
        for (; q + 8 <= qe; q += 8) {                                                      \
            int s0 = FS(q),     s1 = FS(q + 1), s2 = FS(q + 2), s3 = FS(q + 3);            \
            int s4 = FS(q + 4), s5 = FS(q + 5), s6 = FS(q + 6), s7 = FS(q + 7);            \
            float e0 = asp[(size_t)s0 * 8 + h], e1 = asp[(size_t)s1 * 8 + h];              \
            float e2 = asp[(size_t)s2 * 8 + h], e3 = asp[(size_t)s3 * 8 + h];              \
            float e4 = asp[(size_t)s4 * 8 + h], e5 = asp[(size_t)s5 * 8 + h];              \
            float e6 = asp[(size_t)s6 * 8 + h], e7 = asp[(size_t)s7 * 8 + h];              \
            uint2 v0 = h2t2[(size_t)s0 * 18 + j], v1 = h2t2[(size_t)s1 * 18 + j];          \
            uint2 v2 = h2t2[(size_t)s2 * 18 + j], v3 = h2t2[(size_t)s3 * 18 + j];          \
            uint2 v4 = h2t2[(size_t)s4 * 18 + j], v5 = h2t2[(size_t)s5 * 18 + j];          \
            uint2 v6 = h2t2[(size_t)s6 * 18 + j], v7 = h2t2[(size_t)s7 * 18 + j];          \
            G2_EDGE(e0, v0) G2_EDGE(e1, v1) G2_EDGE(e2, v2) G2_EDGE(e3, v3)                \
            G2_EDGE(e4, v4) G2_EDGE(e5, v5) G2_EDGE(e6, v6) G2_EDGE(e7, v7)                \
        }                                                                                  \
        for (; q + 4 <= qe; q += 4) {                                                      \
            int s0 = FS(q), s1 = FS(q + 1), s2 = FS(q + 2), s3 = FS(q + 3);                \
            float e0 = asp[(size_t)s0 * 8 + h], e1 = asp[(size_t)s1 * 8 + h];              \
            float e2 = asp[(size_t)s2 * 8 + h], e3 = asp[(size_t)s3 * 8 + h];              \
            uint2 v0 = h2t2[(size_t)s0 * 18 + j], v1 = h2t2[(size_t)s1 * 18 + j];          \
            uint2 v2 = h2t2[(size_t)s2 * 18 + j], v3 = h2t2[(size_t)s3 * 18 + j];          \
            G2_EDGE(e0, v0) G2_EDGE(e1, v1) G2_EDGE(e2, v2) G2_EDGE(e3, v3)                \
        }                                                                                  \
        for (; q < qe; ++q) {                                                              \
            int s0 = FS(q);                                                                \
            float e0 = asp[(size_t)s0 * 8 + h];                                            \
            uint2 v0 = h2t2[(size_t)s0 * 18 + j];                                          \
            G2_EDGE(e0, v0)                                                                \
        }                                                                                  \
    }
#define G2_SE(i) se[i]
#define G2_GE(i) esrc[i]
        if (staged) {
            int q = p0 - base, qe = p1 - base;
            G2_LOOP(G2_SE)
        } else {
            int q = p0, qe = p1;
            G2_LOOP(G2_GE)
        }
#undef G2_EDGE
#undef G2_LOOP
        float rd = 1.f / (den + 1e-12f);
        int cb = 8 * j;
#pragma unroll
        for (int c = 0; c < 8; ++c) {
            float vv = acc[c] * rd;
            vv = vv > 0.f ? vv : expm1f(vv);
            atomicAdd(&sp[cb + c], vv);
        }
    }
    __syncthreads();
    if (li < 144) atomicAdd(&pooled[li], sp[li]);
}

// ---- out = dot(pooled, Wd) / max(||pooled||, 1e-12) + bd ----
__global__ void final_kernel(const float* __restrict__ pooled, const float* __restrict__ Wd,
                             const float* __restrict__ bd, float* __restrict__ out) {
    int l = threadIdx.x;
    float ss = 0.f, dot = 0.f;
    for (int c = l; c < 144; c += 64) {
        float p = pooled[c];
        ss = fmaf(p, p, ss);
        dot = fmaf(p, Wd[c], dot);
    }
#pragma unroll
    for (int o = 32; o > 0; o >>= 1) {
        ss += __shfl_down(ss, o);
        dot += __shfl_down(dot, o);
    }
    if (l == 0) out[0] = dot / fmaxf(sqrtf(ss), 1e-12f) + bd[0];
}

extern "C" void kernel_launch(void* const* d_in, const int* in_sizes, int n_in,
                              void* d_out, int out_size, void* d_ws, size_t ws_size,
                              hipStream_t stream) {
    const float* x   = (const float*)d_in[0];
    const int*   src = (const int*)  d_in[1];
    const int*   dst = (const int*)  d_in[2];
    const float* W1  = (const float*)d_in[3];
    const float* a1s = (const float*)d_in[4];
    const float* a1d = (const float*)d_in[5];
    const float* W2  = (const float*)d_in[6];
    const float* a2s = (const float*)d_in[7];
    const float* a2d = (const float*)d_in[8];
    const float* Wd  = (const float*)d_in[9];
    const float* bd  = (const float*)d_in[10];

    const int N = NNODES, E = NEDGES;
    float* ws = (float*)d_ws;
    float* xp    = ws;                         // N*12
    float* asp1  = xp + (size_t)N * 12;        // N*8
    float* adp1  = asp1 + (size_t)N * 8;       // N*8
    float* aggX  = adp1 + (size_t)N * 8;       // N*72
    float* out1  = aggX + (size_t)N * 72;      // N*96
    unsigned* h2t = (unsigned*)(out1 + (size_t)N * 96);  // N*36 uints (fp8 x 144); region reserves N*72
    float* asp2  = out1 + (size_t)N * 96 + (size_t)N * 72;  // N*8
    float* adp2  = asp2 + (size_t)N * 8;       // N*8
    float* va1s  = adp2 + (size_t)N * 8;       // 96
    float* va1d  = va1s + 96;                  // 96
    float* va2s  = va1d + 96;                  // 768
    float* va2d  = va2s + 768;                 // 768
    float* pooled = va2d + 768;                // 144
    int*   off   = (int*)(pooled + 144);       // N+1
    int*   esrc  = off + (N + 1);              // E
    unsigned* tmp = (unsigned*)(esrc + E);     // E
    int*   bcnt  = (int*)(tmp + E);            // NB
    int*   bbase = bcnt + NB;                  // NB+1
    int*   bcur  = bbase + (NB + 1);           // NB

    const int B = 256;
    auto grid = [](long total, int b) { return (int)((total + b - 1) / b); };

    // ---- CSR build: 2-level counting sort ----
    hipMemsetAsync(bcnt, 0, NB * sizeof(int), stream);
    bucket_hist_kernel<<<256, 256, 0, stream>>>(dst, bcnt, E);
    bucket_scan_kernel<<<1, 512, 0, stream>>>(bcnt, bbase, bcur, off, E);
    binA_kernel<<<grid(E, BA_CHUNK), BA_THREADS, 0, stream>>>(src, dst, bcur, tmp, E);
    binB_kernel<<<NB, 256, 0, stream>>>(bbase, tmp, off, esrc, N);

    // ---- layer 1 (gather raw x, GEMM after) ----
    padx_kernel<<<grid((long)N * 12, B), B, 0, stream>>>(x, xp, N);
    va_kernel<12, 6, 16><<<1, 96, 0, stream>>>(W1, a1s, a1d, va1s, va1d, 11);
    alphap_kernel<12><<<grid((long)N * 8, B), B, 0, stream>>>(xp, va1s, va1d, asp1, adp1, N);
    gather1_kernel<<<grid(N, G1_NODES), G1_THREADS, 0, stream>>>(off, esrc, asp1, adp1, xp, aggX, N);
    gemmL1_kernel<<<grid((long)N * 24, B), B, 0, stream>>>(aggX, W1, out1, N);

    // ---- layer 2 (fp8 message table, alphas exact f32 from out1) ----
    va_kernel<96, 6, 24><<<1, 768, 0, stream>>>(W2, a2s, a2d, va2s, va2d, 96);
    alphap_kernel<96><<<grid((long)N * 8, B), B, 0, stream>>>(out1, va2s, va2d, asp2, adp2, N);
    gemm_fp8_kernel<96, 144, 2><<<grid((long)(N / 2) * 36, 1024), 1024, 0, stream>>>(out1, W2, h2t, N);
    hipMemsetAsync(pooled, 0, 144 * sizeof(float), stream);
    gather2_kernel<<<grid(N, G2_NODES), G2_THREADS, 0, stream>>>(off, esrc, asp2, adp2,
                                                                 (const uint2*)h2t, pooled, N);

    // ---- normalize + linear ----
    final_kernel<<<1, 64, 0, stream>>>(pooled, Wd, bd, (float*)d_out);
}

// Round 13
// 215.511 us; speedup vs baseline: 1.2051x; 1.2051x over previous
//
#include <hip/hip_runtime.h>
#include <math.h>

#define NNODES 50000
#define NEDGES 1600000
#define NB 391              // ceil(50000/128) buckets of 128 nodes
#define NBP 400             // padded

__device__ __forceinline__ float lrelu(float v) { return v > 0.f ? v : 0.2f * v; }

template<int SEL>
__device__ __forceinline__ float fp8d(unsigned u) {  // decode byte SEL of u (e4m3 OCP)
    return __builtin_amdgcn_cvt_f32_fp8((int)u, SEL);
}

// ---- fused prep: va1, va2, zero bcnt+pooled, pad x -> xp.  768-thr blocks ----
__global__ void prep_kernel(const float* __restrict__ x, float* __restrict__ xp,
                            const float* __restrict__ W1, const float* __restrict__ a1s,
                            const float* __restrict__ a1d, float* __restrict__ va1s,
                            float* __restrict__ va1d,
                            const float* __restrict__ W2, const float* __restrict__ a2s,
                            const float* __restrict__ a2d, float* __restrict__ va2s,
                            float* __restrict__ va2d,
                            int* __restrict__ bcnt, float* __restrict__ pooled, int N) {
    int b = blockIdx.x, t = threadIdx.x;
    if (b == 0) {
        // va1[k][h] = sum_f W1[k][h*16+f]*a1{s,d}[h][f]  (12x8, eff 11x6)
        if (t < 96) {
            int k = t >> 3, h = t & 7;
            float s = 0.f, d = 0.f;
            if (h < 6 && k < 11) {
                for (int f = 0; f < 16; ++f) {
                    float w = W1[k * 96 + h * 16 + f];
                    s = fmaf(w, a1s[h * 16 + f], s);
                    d = fmaf(w, a1d[h * 16 + f], d);
                }
            }
            va1s[t] = s;
            va1d[t] = d;
        }
    } else if (b == 1) {
        // va2[k][h] (96x8, eff 96x6)
        if (t < 768) {
            int k = t >> 3, h = t & 7;
            float s = 0.f, d = 0.f;
            if (h < 6) {
                for (int f = 0; f < 24; ++f) {
                    float w = W2[k * 144 + h * 24 + f];
                    s = fmaf(w, a2s[h * 24 + f], s);
                    d = fmaf(w, a2d[h * 24 + f], d);
                }
            }
            va2s[t] = s;
            va2d[t] = d;
        }
    } else if (b == 2) {
        if (t < NB) bcnt[t] = 0;
        if (t >= 512 && t < 512 + 144) pooled[t - 512] = 0.f;
    } else {
        int i = (b - 3) * 768 + t;
        if (i < N * 12) {
            int n = i / 12, k = i - n * 12;
            xp[i] = (k < 11) ? x[n * 11 + k] : 0.f;
        }
    }
}

// ---- asp[n*8+h] = sum_k X[n][k]*va_s[k][h]; adp likewise ----
template<int DIN>
__global__ void alphap_kernel(const float* __restrict__ X, const float* __restrict__ va_s,
                              const float* __restrict__ va_d, float* __restrict__ asp,
                              float* __restrict__ adp, int N) {
    __shared__ float vs[DIN * 8], vd[DIN * 8];
    for (int i = threadIdx.x; i < DIN * 8; i += blockDim.x) { vs[i] = va_s[i]; vd[i] = va_d[i]; }
    __syncthreads();
    int t = blockIdx.x * blockDim.x + threadIdx.x;
    if (t >= N * 8) return;
    int n = t / 8, h = t - n * 8;
    const float* xr = X + (size_t)n * DIN;
    float s = 0.f, d = 0.f;
    for (int k = 0; k < DIN; ++k) {
        float xv = xr[k];
        s = fmaf(xv, vs[k * 8 + h], s);
        d = fmaf(xv, vd[k * 8 + h], d);
    }
    asp[t] = s;
    adp[t] = d;
}

// ==== CSR build: 2-level counting sort by dst ====
__global__ void bucket_hist_kernel(const int* __restrict__ dst, int* __restrict__ bcnt, int E) {
    __shared__ int h[NBP];
    for (int i = threadIdx.x; i < NBP; i += blockDim.x) h[i] = 0;
    __syncthreads();
    for (int e = blockIdx.x * blockDim.x + threadIdx.x; e < E; e += gridDim.x * blockDim.x)
        atomicAdd(&h[dst[e] >> 7], 1);
    __syncthreads();
    for (int i = threadIdx.x; i < NB; i += blockDim.x)
        if (h[i]) atomicAdd(&bcnt[i], h[i]);
}

__global__ void bucket_scan_kernel(const int* __restrict__ bcnt, int* __restrict__ bbase,
                                   int* __restrict__ bcur, int* __restrict__ off, int E) {
    __shared__ int ls[512];
    int t = threadIdx.x;
    int c = (t < NB) ? bcnt[t] : 0;
    ls[t] = c;
    __syncthreads();
    for (int o = 1; o < 512; o <<= 1) {
        int u = (t >= o) ? ls[t - o] : 0;
        __syncthreads();
        ls[t] += u;
        __syncthreads();
    }
    if (t < NB) {
        int ex = ls[t] - c;
        bbase[t] = ex;
        bcur[t] = ex;
    }
    if (t == 0) { bbase[NB] = E; off[NNODES] = E; }
}

#define BA_CHUNK 8192
#define BA_THREADS 1024
__global__ void binA_kernel(const int* __restrict__ src, const int* __restrict__ dst,
                            int* __restrict__ bcur, unsigned* __restrict__ tmp, int E) {
    __shared__ unsigned sv[BA_CHUNK];
    __shared__ unsigned short sb[BA_CHUNK];
    __shared__ int cnt[NBP], basel[NBP];
    int tid = threadIdx.x;
    for (int i = tid; i < NBP; i += BA_THREADS) cnt[i] = 0;
    __syncthreads();
    int e0 = blockIdx.x * BA_CHUNK;
    int lim = min(BA_CHUNK, E - e0);
#pragma unroll
    for (int k = 0; k < BA_CHUNK / BA_THREADS; ++k) {
        int i = k * BA_THREADS + tid;
        if (i < lim) {
            int s = src[e0 + i], d = dst[e0 + i];
            sv[i] = (unsigned)s | ((unsigned)(d & 127) << 17);
            int b = d >> 7;
            sb[i] = (unsigned short)b;
            atomicAdd(&cnt[b], 1);
        }
    }
    __syncthreads();
    for (int i = tid; i < NB; i += BA_THREADS)
        basel[i] = cnt[i] ? atomicAdd(&bcur[i], cnt[i]) : 0;
    __syncthreads();
#pragma unroll
    for (int k = 0; k < BA_CHUNK / BA_THREADS; ++k) {
        int i = k * BA_THREADS + tid;
        if (i < lim) {
            int pos = atomicAdd(&basel[sb[i]], 1);
            tmp[pos] = sv[i];
        }
    }
}

__global__ void binB_kernel(const int* __restrict__ bbase, const unsigned* __restrict__ tmp,
                            int* __restrict__ off, int* __restrict__ esrc, int N) {
    __shared__ int ncnt[128], ncur[128], ls[128];
    int b = blockIdx.x;
    int tid = threadIdx.x;   // 256 threads
    int lo = bbase[b], hi = bbase[b + 1];
    if (tid < 128) ncnt[tid] = 0;
    __syncthreads();
    for (int i = lo + tid; i < hi; i += 256)
        atomicAdd(&ncnt[tmp[i] >> 17], 1);
    __syncthreads();
    if (tid < 128) ls[tid] = ncnt[tid];
    __syncthreads();
    for (int o = 1; o < 128; o <<= 1) {
        int u = (tid >= o && tid < 128) ? ls[tid - o] : 0;
        __syncthreads();
        if (tid < 128) ls[tid] += u;
        __syncthreads();
    }
    if (tid < 128) {
        int ex = lo + ls[tid] - ncnt[tid];
        int n = b * 128 + tid;
        if (n < N) off[n] = ex;
        ncur[tid] = ex;
    }
    __syncthreads();
    for (int i = lo + tid; i < hi; i += 256) {
        unsigned v = tmp[i];
        int pos = atomicAdd(&ncur[v >> 17], 1);
        esrc[pos] = (int)(v & 0x1FFFFu);
    }
}

// ---- layer-1 gather on raw x rows: 3 thr/node, LDS-staged esrc, unroll-4 ----
#define G1_NODES 128
#define G1_THREADS (G1_NODES * 3)
#define G1_ECAP 4800
__global__ void gather1_kernel(const int* __restrict__ off, const int* __restrict__ esrc,
                               const float* __restrict__ asp, const float* __restrict__ adp,
                               const float* __restrict__ xp, float* __restrict__ aggX, int N) {
    __shared__ int se[G1_ECAP];
    int li = threadIdx.x;
    int n0 = blockIdx.x * G1_NODES;
    int nend = min(n0 + G1_NODES, N);
    int base = off[n0];
    int cnt = off[nend] - base;
    bool staged = (cnt <= G1_ECAP);
    if (staged) for (int i = li; i < cnt; i += G1_THREADS) se[i] = esrc[base + i];
    __syncthreads();
    int node = n0 + li / 3;
    int j = li % 3;
    if (node >= N) return;
    const float4 advA = *(const float4*)(adp + (size_t)node * 8);
    const float2 advB = *(const float2*)(adp + (size_t)node * 8 + 4);
    const float4* xp4 = (const float4*)xp;
    int p0 = off[node], p1 = off[node + 1];
    float4 ac[6];
    float d[6];
#pragma unroll
    for (int u = 0; u < 6; ++u) { ac[u] = make_float4(0.f, 0.f, 0.f, 0.f); d[u] = 0.f; }
#define G1_EDGE(asA, asB, xv)                                                        \
    {                                                                                \
        float a0 = __expf(lrelu(asA.x + advA.x));                                    \
        float a1 = __expf(lrelu(asA.y + advA.y));                                    \
        float a2 = __expf(lrelu(asA.z + advA.z));                                    \
        float a3 = __expf(lrelu(asA.w + advA.w));                                    \
        float a4 = __expf(lrelu(asB.x + advB.x));                                    \
        float a5 = __expf(lrelu(asB.y + advB.y));                                    \
        d[0] += a0; d[1] += a1; d[2] += a2; d[3] += a3; d[4] += a4; d[5] += a5;      \
        ac[0].x = fmaf(a0, xv.x, ac[0].x); ac[0].y = fmaf(a0, xv.y, ac[0].y);        \
        ac[0].z = fmaf(a0, xv.z, ac[0].z); ac[0].w = fmaf(a0, xv.w, ac[0].w);        \
        ac[1].x = fmaf(a1, xv.x, ac[1].x); ac[1].y = fmaf(a1, xv.y, ac[1].y);        \
        ac[1].z = fmaf(a1, xv.z, ac[1].z); ac[1].w = fmaf(a1, xv.w, ac[1].w);        \
        ac[2].x = fmaf(a2, xv.x, ac[2].x); ac[2].y = fmaf(a2, xv.y, ac[2].y);        \
        ac[2].z = fmaf(a2, xv.z, ac[2].z); ac[2].w = fmaf(a2, xv.w, ac[2].w);        \
        ac[3].x = fmaf(a3, xv.x, ac[3].x); ac[3].y = fmaf(a3, xv.y, ac[3].y);        \
        ac[3].z = fmaf(a3, xv.z, ac[3].z); ac[3].w = fmaf(a3, xv.w, ac[3].w);        \
        ac[4].x = fmaf(a4, xv.x, ac[4].x); ac[4].y = fmaf(a4, xv.y, ac[4].y);        \
        ac[4].z = fmaf(a4, xv.z, ac[4].z); ac[4].w = fmaf(a4, xv.w, ac[4].w);        \
        ac[5].x = fmaf(a5, xv.x, ac[5].x); ac[5].y = fmaf(a5, xv.y, ac[5].y);        \
        ac[5].z = fmaf(a5, xv.z, ac[5].z); ac[5].w = fmaf(a5, xv.w, ac[5].w);        \
    }
#define G1_LOOP(FS)                                                                  \
    {                                                                                \
        for (; q + 4 <= qe; q += 4) {                                                \
            int s0 = FS(q), s1 = FS(q + 1), s2 = FS(q + 2), s3 = FS(q + 3);          \
            float4 A0 = *(const float4*)(asp + (size_t)s0 * 8);                      \
            float2 B0 = *(const float2*)(asp + (size_t)s0 * 8 + 4);                  \
            float4 X0 = xp4[(size_t)s0 * 3 + j];                                     \
            float4 A1 = *(const float4*)(asp + (size_t)s1 * 8);                      \
            float2 B1 = *(const float2*)(asp + (size_t)s1 * 8 + 4);                  \
            float4 X1 = xp4[(size_t)s1 * 3 + j];                                     \
            float4 A2 = *(const float4*)(asp + (size_t)s2 * 8);                      \
            float2 B2 = *(const float2*)(asp + (size_t)s2 * 8 + 4);                  \
            float4 X2 = xp4[(size_t)s2 * 3 + j];                                     \
            float4 A3 = *(const float4*)(asp + (size_t)s3 * 8);                      \
            float2 B3 = *(const float2*)(asp + (size_t)s3 * 8 + 4);                  \
            float4 X3 = xp4[(size_t)s3 * 3 + j];                                     \
            G1_EDGE(A0, B0, X0) G1_EDGE(A1, B1, X1)                                  \
            G1_EDGE(A2, B2, X2) G1_EDGE(A3, B3, X3)                                  \
        }                                                                            \
        for (; q < qe; ++q) {                                                        \
            int s0 = FS(q);                                                          \
            float4 A0 = *(const float4*)(asp + (size_t)s0 * 8);                      \
            float2 B0 = *(const float2*)(asp + (size_t)s0 * 8 + 4);                  \
            float4 X0 = xp4[(size_t)s0 * 3 + j];                                     \
            G1_EDGE(A0, B0, X0)                                                      \
        }                                                                            \
    }
#define G1_SE(i) se[i]
#define G1_GE(i) esrc[i]
    if (staged) {
        int q = p0 - base, qe = p1 - base;
        G1_LOOP(G1_SE)
    } else {
        int q = p0, qe = p1;
        G1_LOOP(G1_GE)
    }
#undef G1_EDGE
#undef G1_LOOP
    float4* o4 = (float4*)aggX;
#pragma unroll
    for (int u = 0; u < 6; ++u) {
        float r = 1.f / (d[u] + 1e-12f);
        float4 a = ac[u];
        a.x *= r; a.y *= r; a.z *= r; a.w *= r;
        o4[((size_t)node * 6 + u) * 3 + j] = a;
    }
}

// ---- out1[n][96] = elu( aggX[n][h] @ W1[:, head block] ) ----
__global__ void gemmL1_kernel(const float* __restrict__ aggX, const float* __restrict__ W1,
                              float* __restrict__ out1, int N) {
    __shared__ float Wl[12 * 96];
    for (int i = threadIdx.x; i < 12 * 96; i += blockDim.x) Wl[i] = (i < 11 * 96) ? W1[i] : 0.f;
    __syncthreads();
    int t = blockIdx.x * blockDim.x + threadIdx.x;
    if (t >= N * 24) return;
    int n = t / 24, q = t - n * 24;
    int h = q / 4, c = q * 4;
    const float* ag = aggX + ((size_t)n * 6 + h) * 12;
    float4 acc = {0, 0, 0, 0};
#pragma unroll
    for (int k = 0; k < 12; ++k) {
        float xv = ag[k];
        acc.x = fmaf(xv, Wl[k * 96 + c + 0], acc.x);
        acc.y = fmaf(xv, Wl[k * 96 + c + 1], acc.y);
        acc.z = fmaf(xv, Wl[k * 96 + c + 2], acc.z);
        acc.w = fmaf(xv, Wl[k * 96 + c + 3], acc.w);
    }
    acc.x = acc.x > 0.f ? acc.x : expm1f(acc.x);
    acc.y = acc.y > 0.f ? acc.y : expm1f(acc.y);
    acc.z = acc.z > 0.f ? acc.z : expm1f(acc.z);
    acc.w = acc.w > 0.f ? acc.w : expm1f(acc.w);
    ((float4*)out1)[(size_t)n * 24 + q] = acc;
}

// ---- h2 = out1 @ W2, stored fp8 e4m3 (HW RNE cvt); float4 X loads; 1024-thr blocks ----
template<int DIN, int C, int NPT>
__global__ void gemm_fp8_kernel(const float* __restrict__ X, const float* __restrict__ W,
                                unsigned* __restrict__ Out, int N) {
    constexpr int Q = C / 4;
    __shared__ float4 Wl[DIN * Q];
    for (int i = threadIdx.x; i < DIN * Q; i += blockDim.x) Wl[i] = ((const float4*)W)[i];
    __syncthreads();
    int t = blockIdx.x * blockDim.x + threadIdx.x;
    int g = t / Q, q = t - g * Q;
    int n0 = g * NPT;
    if (n0 >= N) return;
    const float4* X4 = (const float4*)X;
    float4 acc[NPT];
#pragma unroll
    for (int u = 0; u < NPT; ++u) acc[u] = make_float4(0.f, 0.f, 0.f, 0.f);
#pragma unroll 2
    for (int k4 = 0; k4 < DIN / 4; ++k4) {
        float4 xv[NPT];
#pragma unroll
        for (int u = 0; u < NPT; ++u) xv[u] = X4[(size_t)(n0 + u) * (DIN / 4) + k4];
#pragma unroll
        for (int i = 0; i < 4; ++i) {
            float4 w = Wl[(k4 * 4 + i) * Q + q];
#pragma unroll
            for (int u = 0; u < NPT; ++u) {
                float xs = (i == 0) ? xv[u].x : (i == 1) ? xv[u].y : (i == 2) ? xv[u].z : xv[u].w;
                acc[u].x = fmaf(xs, w.x, acc[u].x);
                acc[u].y = fmaf(xs, w.y, acc[u].y);
                acc[u].z = fmaf(xs, w.z, acc[u].z);
                acc[u].w = fmaf(xs, w.w, acc[u].w);
            }
        }
    }
#pragma unroll
    for (int u = 0; u < NPT; ++u) {
        int pk = __builtin_amdgcn_cvt_pk_fp8_f32(acc[u].x, acc[u].y, 0, false);
        pk     = __builtin_amdgcn_cvt_pk_fp8_f32(acc[u].z, acc[u].w, pk, true);
        Out[(size_t)(n0 + u) * Q + q] = (unsigned)pk;
    }
}

// ---- layer-2 gather: 18 thr/node (one uint2 = 8 fp8 ch each), LDS-staged esrc,
//      unroll-4, fused elu + block pool.  block = 512 thr (8 waves) = 28 nodes x 18 ----
#define G2_NODES 28
#define G2_TPN 18
#define G2_THREADS 512
#define G2_ACTIVE (G2_NODES * G2_TPN)   // 504
#define G2_ECAP 1600
__global__ void gather2_kernel(const int* __restrict__ off, const int* __restrict__ esrc,
                               const float* __restrict__ asp, const float* __restrict__ adp,
                               const uint2* __restrict__ h2t2, float* __restrict__ pooled, int N) {
    __shared__ float sp[144];
    __shared__ int se[G2_ECAP];
    int li = threadIdx.x;
    int n0 = blockIdx.x * G2_NODES;
    int nend = min(n0 + G2_NODES, N);
    int base = off[n0];
    int cnt = off[nend] - base;
    bool staged = (cnt <= G2_ECAP);
    if (staged) for (int i = li; i < cnt; i += G2_THREADS) se[i] = esrc[base + i];
    if (li < 144) sp[li] = 0.f;
    __syncthreads();
    int node = n0 + li / G2_TPN;
    int j = li % G2_TPN;        // channels [8j, 8j+8)
    if (li < G2_ACTIVE && node < N) {
        int h = j / 3;          // 24 ch per head = 3 uint2 per head
        float adv = adp[(size_t)node * 8 + h];
        int p0 = off[node], p1 = off[node + 1];
        float acc[8];
#pragma unroll
        for (int c = 0; c < 8; ++c) acc[c] = 0.f;
        float den = 0.f;
#define G2_EDGE(ev, v)                                                     \
    {                                                                      \
        float att = __expf(lrelu(ev + adv));                               \
        den += att;                                                        \
        acc[0] = fmaf(att, fp8d<0>(v.x), acc[0]);                          \
        acc[1] = fmaf(att, fp8d<1>(v.x), acc[1]);                          \
        acc[2] = fmaf(att, fp8d<2>(v.x), acc[2]);                          \
        acc[3] = fmaf(att, fp8d<3>(v.x), acc[3]);                          \
        acc[4] = fmaf(att, fp8d<0>(v.y), acc[4]);                          \
        acc[5] = fmaf(att, fp8d<1>(v.y), acc[5]);                          \
        acc[6] = fmaf(att, fp8d<2>(v.y), acc[6]);                          \
        acc[7] = fmaf(att, fp8d<3>(v.y), acc[7]);                          \
    }
#define G2_LOOP(FS)                                                                        \
    {                                                                                      \
        for (; q + 4 <= qe; q += 4) {                                                      \
            int s0 = FS(q), s1 = FS(q + 1), s2 = FS(q + 2), s3 = FS(q + 3);                \
            float e0 = asp[(size_t)s0 * 8 + h], e1 = asp[(size_t)s1 * 8 + h];              \
            float e2 = asp[(size_t)s2 * 8 + h], e3 = asp[(size_t)s3 * 8 + h];              \
            uint2 v0 = h2t2[(size_t)s0 * 18 + j], v1 = h2t2[(size_t)s1 * 18 + j];          \
            uint2 v2 = h2t2[(size_t)s2 * 18 + j], v3 = h2t2[(size_t)s3 * 18 + j];          \
            G2_EDGE(e0, v0) G2_EDGE(e1, v1) G2_EDGE(e2, v2) G2_EDGE(e3, v3)                \
        }                                                                                  \
        for (; q < qe; ++q) {                                                              \
            int s0 = FS(q);                                                                \
            float e0 = asp[(size_t)s0 * 8 + h];                                            \
            uint2 v0 = h2t2[(size_t)s0 * 18 + j];                                          \
            G2_EDGE(e0, v0)                                                                \
        }                                                                                  \
    }
#define G2_SE(i) se[i]
#define G2_GE(i) esrc[i]
        if (staged) {
            int q = p0 - base, qe = p1 - base;
            G2_LOOP(G2_SE)
        } else {
            int q = p0, qe = p1;
            G2_LOOP(G2_GE)
        }
#undef G2_EDGE
#undef G2_LOOP
        float rd = 1.f / (den + 1e-12f);
        int cb = 8 * j;
#pragma unroll
        for (int c = 0; c < 8; ++c) {
            float vv = acc[c] * rd;
            vv = vv > 0.f ? vv : expm1f(vv);
            atomicAdd(&sp[cb + c], vv);
        }
    }
    __syncthreads();
    if (li < 144) atomicAdd(&pooled[li], sp[li]);
}

// ---- out = dot(pooled, Wd) / max(||pooled||, 1e-12) + bd ----
__global__ void final_kernel(const float* __restrict__ pooled, const float* __restrict__ Wd,
                             const float* __restrict__ bd, float* __restrict__ out) {
    int l = threadIdx.x;
    float ss = 0.f, dot = 0.f;
    for (int c = l; c < 144; c += 64) {
        float p = pooled[c];
        ss = fmaf(p, p, ss);
        dot = fmaf(p, Wd[c], dot);
    }
#pragma unroll
    for (int o = 32; o > 0; o >>= 1) {
        ss += __shfl_down(ss, o);
        dot += __shfl_down(dot, o);
    }
    if (l == 0) out[0] = dot / fmaxf(sqrtf(ss), 1e-12f) + bd[0];
}

extern "C" void kernel_launch(void* const* d_in, const int* in_sizes, int n_in,
                              void* d_out, int out_size, void* d_ws, size_t ws_size,
                              hipStream_t stream) {
    const float* x   = (const float*)d_in[0];
    const int*   src = (const int*)  d_in[1];
    const int*   dst = (const int*)  d_in[2];
    const float* W1  = (const float*)d_in[3];
    const float* a1s = (const float*)d_in[4];
    const float* a1d = (const float*)d_in[5];
    const float* W2  = (const float*)d_in[6];
    const float* a2s = (const float*)d_in[7];
    const float* a2d = (const float*)d_in[8];
    const float* Wd  = (const float*)d_in[9];
    const float* bd  = (const float*)d_in[10];

    const int N = NNODES, E = NEDGES;
    float* ws = (float*)d_ws;
    float* xp    = ws;                         // N*12
    float* asp1  = xp + (size_t)N * 12;        // N*8
    float* adp1  = asp1 + (size_t)N * 8;       // N*8
    float* aggX  = adp1 + (size_t)N * 8;       // N*72
    float* out1  = aggX + (size_t)N * 72;      // N*96
    unsigned* h2t = (unsigned*)(out1 + (size_t)N * 96);  // N*36 uints (fp8 x 144); region reserves N*72
    float* asp2  = out1 + (size_t)N * 96 + (size_t)N * 72;  // N*8
    float* adp2  = asp2 + (size_t)N * 8;       // N*8
    float* va1s  = adp2 + (size_t)N * 8;       // 96
    float* va1d  = va1s + 96;                  // 96
    float* va2s  = va1d + 96;                  // 768
    float* va2d  = va2s + 768;                 // 768
    float* pooled = va2d + 768;                // 144
    int*   off   = (int*)(pooled + 144);       // N+1
    int*   esrc  = off + (N + 1);              // E
    unsigned* tmp = (unsigned*)(esrc + E);     // E
    int*   bcnt  = (int*)(tmp + E);            // NB
    int*   bbase = bcnt + NB;                  // NB+1
    int*   bcur  = bbase + (NB + 1);           // NB

    const int B = 256;
    auto grid = [](long total, int b) { return (int)((total + b - 1) / b); };

    // ---- fused prep: va1, va2, zero bcnt+pooled, padx ----
    prep_kernel<<<3 + grid((long)N * 12, 768), 768, 0, stream>>>(
        x, xp, W1, a1s, a1d, va1s, va1d, W2, a2s, a2d, va2s, va2d, bcnt, pooled, N);

    // ---- CSR build: 2-level counting sort ----
    bucket_hist_kernel<<<256, 256, 0, stream>>>(dst, bcnt, E);
    bucket_scan_kernel<<<1, 512, 0, stream>>>(bcnt, bbase, bcur, off, E);
    binA_kernel<<<grid(E, BA_CHUNK), BA_THREADS, 0, stream>>>(src, dst, bcur, tmp, E);
    binB_kernel<<<NB, 256, 0, stream>>>(bbase, tmp, off, esrc, N);

    // ---- layer 1 (gather raw x, GEMM after) ----
    alphap_kernel<12><<<grid((long)N * 8, B), B, 0, stream>>>(xp, va1s, va1d, asp1, adp1, N);
    gather1_kernel<<<grid(N, G1_NODES), G1_THREADS, 0, stream>>>(off, esrc, asp1, adp1, xp, aggX, N);
    gemmL1_kernel<<<grid((long)N * 24, B), B, 0, stream>>>(aggX, W1, out1, N);

    // ---- layer 2 (fp8 message table, alphas exact f32 from out1) ----
    alphap_kernel<96><<<grid((long)N * 8, B), B, 0, stream>>>(out1, va2s, va2d, asp2, adp2, N);
    gemm_fp8_kernel<96, 144, 2><<<grid((long)(N / 2) * 36, 1024), 1024, 0, stream>>>(out1, W2, h2t, N);
    gather2_kernel<<<grid(N, G2_NODES), G2_THREADS, 0, stream>>>(off, esrc, asp2, adp2,
                                                                 (const uint2*)h2t, pooled, N);

    // ---- normalize + linear ----
    final_kernel<<<1, 64, 0, stream>>>(pooled, Wd, bd, (float*)d_out);
}